// Round 5
// baseline (53.277 us; speedup 1.0000x reference)
//
#include <hip/hip_runtime.h>

#define BLOCK 256
#define TPB 8            // true boxes per thread (8 independent dep chains)
#define SPLIT_N 256      // N-split: 4 x 256 = 1024 blocks = 4 waves/SIMD

// Fix pred+true boxes into workspace; no atomics anywhere.
__global__ void fix_kernel(const float* __restrict__ pred,
                           const float* __restrict__ trub,
                           float4* __restrict__ pf, float* __restrict__ pa,
                           float4* __restrict__ tf, float* __restrict__ tta,
                           int N, int M) {
    int i = blockIdx.x * blockDim.x + threadIdx.x;
    if (i < N) {
        float4 b = reinterpret_cast<const float4*>(pred)[i];
        float x1 = fminf(b.x, b.z), y1 = fminf(b.y, b.w);
        float x2 = fmaxf(b.x, b.z), y2 = fmaxf(b.y, b.w);
        x2 = fmaxf(x2, x1 + 1.0f);   // EPS = 1.0
        y2 = fmaxf(y2, y1 + 1.0f);
        pf[i] = make_float4(x1, y1, x2, y2);
        pa[i] = (x2 - x1) * (y2 - y1);
    }
    if (i < M) {
        float4 b = reinterpret_cast<const float4*>(trub)[i];
        float x1 = fminf(b.x, b.z), y1 = fminf(b.y, b.w);
        float x2 = fmaxf(b.x, b.z), y2 = fmaxf(b.y, b.w);
        x2 = fmaxf(x2, x1 + 1.0f);
        y2 = fmaxf(y2, y1 + 1.0f);
        tf[i] = make_float4(x1, y1, x2, y2);
        tta[i] = (x2 - x1) * (y2 - y1);
    }
}

__global__ __launch_bounds__(BLOCK) void iou_max_kernel(
    const float4* __restrict__ pf,   // [N] fixed pred boxes
    const float*  __restrict__ pa,   // [N] pred areas
    const float4* __restrict__ tf,   // [M] fixed true boxes
    const float*  __restrict__ tta,  // [M] true areas
    float* __restrict__ partial,     // [SPLIT_N][M] partial maxima
    int N, int M)
{
    const int chunk = (N + gridDim.y - 1) / (int)gridDim.y;
    const int n0 = blockIdx.y * chunk;
    const int n1 = min(N, n0 + chunk);

    // ---- load my TPB pre-fixed true boxes into registers ----
    const int jbase = blockIdx.x * (BLOCK * TPB) + threadIdx.x;
    float tx1[TPB], ty1[TPB], tx2[TPB], ty2[TPB], ta[TPB], best[TPB];
#pragma unroll
    for (int t = 0; t < TPB; ++t) {
        int j = jbase + t * BLOCK;
        int js = (j < M) ? j : (M - 1);   // safe clamp; best unused if j>=M
        float4 b = tf[js];
        tx1[t] = b.x; ty1[t] = b.y; tx2[t] = b.z; ty2[t] = b.w;
        ta[t]  = tta[js];
        best[t] = 0.0f;
    }

    // ---- scan pred chunk: uniform index -> broadcast loads, no barriers ----
#pragma unroll 8
    for (int k = n0; k < n1; ++k) {
        float4 p   = pf[k];
        float  par = pa[k];
#pragma unroll
        for (int t = 0; t < TPB; ++t) {
            float lx = fmaxf(p.x, tx1[t]);
            float ly = fmaxf(p.y, ty1[t]);
            float rx = fminf(p.z, tx2[t]);
            float ry = fminf(p.w, ty2[t]);
            float w  = fmaxf(rx - lx, 0.0f);
            float h  = fmaxf(ry - ly, 0.0f);
            float inter = w * h;
            float uni   = (par + ta[t]) - inter;
            // uni >= 1 always (EPS forces area >= 1); v_rcp_f32 ~1ulp
            best[t] = fmaxf(best[t], inter * __builtin_amdgcn_rcpf(uni));
        }
    }

    // ---- plain coalesced stores of partials (no atomics) ----
    float* prow = partial + (size_t)blockIdx.y * M;
#pragma unroll
    for (int t = 0; t < TPB; ++t) {
        int j = jbase + t * BLOCK;
        if (j < M) prow[j] = best[t];
    }
}

__global__ __launch_bounds__(BLOCK) void reduce_kernel(
    const float* __restrict__ partial,  // [S][M]
    float* __restrict__ out, int M, int S)
{
    int j = blockIdx.x * BLOCK + threadIdx.x;
    if (j >= M) return;
    float best = 0.0f;
#pragma unroll 8
    for (int s = 0; s < S; ++s)
        best = fmaxf(best, partial[(size_t)s * M + j]);
    out[j] = 1.0f - best;
}

extern "C" void kernel_launch(void* const* d_in, const int* in_sizes, int n_in,
                              void* d_out, int out_size, void* d_ws, size_t ws_size,
                              hipStream_t stream) {
    const float* pred = (const float*)d_in[0];
    const float* trub = (const float*)d_in[1];
    float* out = (float*)d_out;
    const int N = in_sizes[0] / 4;
    const int M = in_sizes[1] / 4;

    // carve workspace
    char* ws = (char*)d_ws;
    size_t off = 0;
    float4* pf  = (float4*)(ws + off); off += (size_t)N * 16;
    float*  pa  = (float*) (ws + off); off += (size_t)N * 4;
    float4* tf  = (float4*)(ws + off); off += (size_t)M * 16;
    float*  tta = (float*) (ws + off); off += (size_t)M * 4;
    off = (off + 255) & ~(size_t)255;
    float* partial = (float*)(ws + off);   // SPLIT_N * M floats (8 MB)

    int mx = max(N, M);
    fix_kernel<<<(mx + BLOCK - 1) / BLOCK, BLOCK, 0, stream>>>(
        pred, trub, pf, pa, tf, tta, N, M);

    dim3 grid((M + BLOCK * TPB - 1) / (BLOCK * TPB), SPLIT_N);
    iou_max_kernel<<<grid, BLOCK, 0, stream>>>(pf, pa, tf, tta, partial, N, M);

    reduce_kernel<<<(M + BLOCK - 1) / BLOCK, BLOCK, 0, stream>>>(
        partial, out, M, SPLIT_N);
}

// Round 6
// 38.002 us; speedup vs baseline: 1.4019x; 1.4019x over previous
//
#include <hip/hip_runtime.h>

#define BLOCK 256
#define TPB 8            // true boxes per thread
#define SPLIT 256        // N-split: 4 x 256 = 1024 blocks = 4 blocks/CU
#define RED_COLS 64      // reduce: columns per block
#define RED_SG 4         // reduce: s-groups per block (256 threads = 64x4)

// ws layout (carved in kernel_launch):
//   flag (int) | pxy[N] f2 | txy[M] f2 | pf[N] f4 | pa[N] f | tf[M] f4 | ta[M] f | partial[SPLIT][M]

__global__ void init_flag(int* flag) { *flag = 0; }

__global__ void fix_kernel(const float* __restrict__ pred,
                           const float* __restrict__ trub,
                           float2* __restrict__ pxy, float4* __restrict__ pf, float* __restrict__ pa,
                           float2* __restrict__ txy, float4* __restrict__ tf, float* __restrict__ ta,
                           int* __restrict__ flag, int N, int M)
{
    int i = blockIdx.x * blockDim.x + threadIdx.x;
    bool bad = false;
    if (i < N) {
        float4 b = reinterpret_cast<const float4*>(pred)[i];
        float x1 = fminf(b.x, b.z), y1 = fminf(b.y, b.w);
        float x2 = fmaxf(b.x, b.z), y2 = fmaxf(b.y, b.w);
        bad = (x2 > x1 + 1.0f) || (y2 > y1 + 1.0f);   // unit-box property check
        x2 = fmaxf(x2, x1 + 1.0f); y2 = fmaxf(y2, y1 + 1.0f);
        pxy[i] = make_float2(x1, y1);
        pf[i]  = make_float4(x1, y1, x2, y2);
        pa[i]  = (x2 - x1) * (y2 - y1);
    }
    if (i < M) {
        float4 b = reinterpret_cast<const float4*>(trub)[i];
        float x1 = fminf(b.x, b.z), y1 = fminf(b.y, b.w);
        float x2 = fmaxf(b.x, b.z), y2 = fmaxf(b.y, b.w);
        bad = bad || (x2 > x1 + 1.0f) || (y2 > y1 + 1.0f);
        x2 = fmaxf(x2, x1 + 1.0f); y2 = fmaxf(y2, y1 + 1.0f);
        txy[i] = make_float2(x1, y1);
        tf[i]  = make_float4(x1, y1, x2, y2);
        ta[i]  = (x2 - x1) * (y2 - y1);
    }
    if (bad) atomicOr(flag, 1);
}

__global__ __launch_bounds__(BLOCK) void iou_main(
    const float2* __restrict__ pxy, const float2* __restrict__ txy,
    const float4* __restrict__ pf,  const float*  __restrict__ pa,
    const float4* __restrict__ tf,  const float*  __restrict__ ta,
    const int* __restrict__ flag,
    float* __restrict__ partial, int N, int M)
{
    const int chunk = (N + gridDim.y - 1) / (int)gridDim.y;
    const int n0 = blockIdx.y * chunk;
    const int n1 = min(N, n0 + chunk);
    const int jbase = blockIdx.x * (BLOCK * TPB) + threadIdx.x;

    float best[TPB];
#pragma unroll
    for (int t = 0; t < TPB; ++t) best[t] = 0.0f;

    if (*flag == 0) {
        // ---- fast path: all boxes are exactly 1x1; track max INTERSECTION ----
        float tx[TPB], ty[TPB];
#pragma unroll
        for (int t = 0; t < TPB; ++t) {
            int j = jbase + t * BLOCK;
            float2 c = txy[(j < M) ? j : (M - 1)];
            tx[t] = c.x; ty[t] = c.y;
        }
#pragma unroll 4
        for (int k = n0; k < n1; ++k) {
            float2 p = pxy[k];
#pragma unroll
            for (int t = 0; t < TPB; ++t) {
                float wx = 1.0f - fabsf(p.x - tx[t]);            // may be negative
                float hy = fmaxf(1.0f - fabsf(p.y - ty[t]), 0.0f); // clamped
                // if wx<0: wx*hy <= 0, discarded by fmax (best >= 0)
                best[t] = fmaxf(best[t], wx * hy);
            }
        }
    } else {
        // ---- generic path: full IoU (any box geometry) ----
        float x1[TPB], y1[TPB], x2[TPB], y2[TPB], a[TPB];
#pragma unroll
        for (int t = 0; t < TPB; ++t) {
            int j = jbase + t * BLOCK;
            int js = (j < M) ? j : (M - 1);
            float4 b = tf[js];
            x1[t] = b.x; y1[t] = b.y; x2[t] = b.z; y2[t] = b.w;
            a[t] = ta[js];
        }
#pragma unroll 2
        for (int k = n0; k < n1; ++k) {
            float4 p = pf[k];
            float par = pa[k];
#pragma unroll
            for (int t = 0; t < TPB; ++t) {
                float lx = fmaxf(p.x, x1[t]);
                float ly = fmaxf(p.y, y1[t]);
                float rx = fminf(p.z, x2[t]);
                float ry = fminf(p.w, y2[t]);
                float w  = fmaxf(rx - lx, 0.0f);
                float h  = fmaxf(ry - ly, 0.0f);
                float inter = w * h;
                float uni   = (par + a[t]) - inter;   // >= 1 (EPS forces dims >= 1)
                best[t] = fmaxf(best[t], inter * __builtin_amdgcn_rcpf(uni));
            }
        }
    }

    // ---- plain coalesced partial stores ----
    float* prow = partial + (size_t)blockIdx.y * M;
#pragma unroll
    for (int t = 0; t < TPB; ++t) {
        int j = jbase + t * BLOCK;
        if (j < M) prow[j] = best[t];
    }
}

__global__ __launch_bounds__(BLOCK) void reduce_kernel(
    const float* __restrict__ partial,  // [S][M]
    const int* __restrict__ flag,
    float* __restrict__ out, int M, int S)
{
    __shared__ float sd[RED_SG][RED_COLS];
    const int c  = threadIdx.x & (RED_COLS - 1);
    const int sg = threadIdx.x >> 6;            // 0..RED_SG-1
    const int j  = blockIdx.x * RED_COLS + c;

    float b = 0.0f;
    if (j < M) {
#pragma unroll 8
        for (int s = sg; s < S; s += RED_SG)
            b = fmaxf(b, partial[(size_t)s * M + j]);
    }
    sd[sg][c] = b;
    __syncthreads();
    if (sg == 0 && j < M) {
        b = fmaxf(fmaxf(sd[0][c], sd[1][c]), fmaxf(sd[2][c], sd[3][c]));
        float loss;
        if (*flag == 0) {
            // b = max intersection; IoU = b/(2-b) (unit boxes), monotone transform
            loss = 1.0f - b * __builtin_amdgcn_rcpf(2.0f - b);  // 2-b in [1,2]
        } else {
            loss = 1.0f - b;   // b = max IoU directly
        }
        out[j] = loss;
    }
}

extern "C" void kernel_launch(void* const* d_in, const int* in_sizes, int n_in,
                              void* d_out, int out_size, void* d_ws, size_t ws_size,
                              hipStream_t stream) {
    const float* pred = (const float*)d_in[0];
    const float* trub = (const float*)d_in[1];
    float* out = (float*)d_out;
    const int N = in_sizes[0] / 4;
    const int M = in_sizes[1] / 4;

    char* ws = (char*)d_ws;
    size_t off = 0;
    int*    flag = (int*)(ws + off);   off += 256;   // keep alignment
    float2* pxy  = (float2*)(ws + off); off += (size_t)N * 8;
    float2* txy  = (float2*)(ws + off); off += (size_t)M * 8;
    float4* pf   = (float4*)(ws + off); off += (size_t)N * 16;
    float*  pa   = (float*) (ws + off); off += (size_t)N * 4;
    float4* tf   = (float4*)(ws + off); off += (size_t)M * 16;
    float*  ta   = (float*) (ws + off); off += (size_t)M * 4;
    off = (off + 255) & ~(size_t)255;
    float* partial = (float*)(ws + off);             // SPLIT * M floats

    init_flag<<<1, 1, 0, stream>>>(flag);

    int mx = max(N, M);
    fix_kernel<<<(mx + BLOCK - 1) / BLOCK, BLOCK, 0, stream>>>(
        pred, trub, pxy, pf, pa, txy, tf, ta, flag, N, M);

    dim3 grid((M + BLOCK * TPB - 1) / (BLOCK * TPB), SPLIT);
    iou_main<<<grid, BLOCK, 0, stream>>>(pxy, txy, pf, pa, tf, ta, flag, partial, N, M);

    reduce_kernel<<<(M + RED_COLS - 1) / RED_COLS, BLOCK, 0, stream>>>(
        partial, flag, out, M, SPLIT);
}

// Round 7
// 32.577 us; speedup vs baseline: 1.6354x; 1.1665x over previous
//
#include <hip/hip_runtime.h>

#define BLOCK 256
#define TPB 8            // true boxes (columns) per thread
#define CHUNK 32         // preds per block, held entirely in registers
#define RED_COLS 32      // reduce: columns per block
#define RED_SG 8         // reduce: s-groups per block (256 = 32 x 8)

// ws layout: flag | pxy[N] f2 | txy[M] f2 | pf[N] f4 | pa[N] f | tf[M] f4 | ta[M] f | partial[S][M]

__global__ void fix_kernel(const float* __restrict__ pred,
                           const float* __restrict__ trub,
                           float2* __restrict__ pxy, float4* __restrict__ pf, float* __restrict__ pa,
                           float2* __restrict__ txy, float4* __restrict__ tf, float* __restrict__ ta,
                           int* __restrict__ flag, int N, int M)
{
    int i = blockIdx.x * blockDim.x + threadIdx.x;
    bool bad = false;
    if (i < N) {
        float4 b = reinterpret_cast<const float4*>(pred)[i];
        float x1 = fminf(b.x, b.z), y1 = fminf(b.y, b.w);
        float x2 = fmaxf(b.x, b.z), y2 = fmaxf(b.y, b.w);
        bad = (x2 > x1 + 1.0f) || (y2 > y1 + 1.0f);   // unit-box property check
        x2 = fmaxf(x2, x1 + 1.0f); y2 = fmaxf(y2, y1 + 1.0f);  // EPS = 1.0
        pxy[i] = make_float2(x1, y1);
        pf[i]  = make_float4(x1, y1, x2, y2);
        pa[i]  = (x2 - x1) * (y2 - y1);
    }
    if (i < M) {
        float4 b = reinterpret_cast<const float4*>(trub)[i];
        float x1 = fminf(b.x, b.z), y1 = fminf(b.y, b.w);
        float x2 = fmaxf(b.x, b.z), y2 = fmaxf(b.y, b.w);
        bad = bad || (x2 > x1 + 1.0f) || (y2 > y1 + 1.0f);
        x2 = fmaxf(x2, x1 + 1.0f); y2 = fmaxf(y2, y1 + 1.0f);
        txy[i] = make_float2(x1, y1);
        tf[i]  = make_float4(x1, y1, x2, y2);
        ta[i]  = (x2 - x1) * (y2 - y1);
    }
    if (bad) atomicOr(flag, 1);
}

__global__ __launch_bounds__(BLOCK) void iou_main(
    const float2* __restrict__ pxy, const float2* __restrict__ txy,
    const float4* __restrict__ pf,  const float*  __restrict__ pa,
    const float4* __restrict__ tf,  const float*  __restrict__ ta,
    const int* __restrict__ flag,
    float* __restrict__ partial, int N, int M)
{
    const int n0 = blockIdx.y * CHUNK;
    const int jbase = blockIdx.x * (BLOCK * TPB) + threadIdx.x;

    float best[TPB];
#pragma unroll
    for (int t = 0; t < TPB; ++t) best[t] = 0.0f;

    if (*flag == 0) {
        // ---- fast path: all boxes exactly 1x1; track max INTERSECTION ----
        // preload whole pred chunk into registers (index-clamp = duplicate,
        // harmless for max); ONE vmcnt wait, then a pure-VALU unrolled loop.
        float2 c2[CHUNK];
#pragma unroll
        for (int i = 0; i < CHUNK; ++i)
            c2[i] = pxy[min(n0 + i, N - 1)];

        float tx[TPB], ty[TPB];
#pragma unroll
        for (int t = 0; t < TPB; ++t) {
            int j = jbase + t * BLOCK;
            float2 c = txy[(j < M) ? j : (M - 1)];
            tx[t] = c.x; ty[t] = c.y;
        }
#pragma unroll
        for (int k = 0; k < CHUNK; ++k) {      // FULL unroll: c2[k] static
            float px = c2[k].x, py = c2[k].y;
#pragma unroll
            for (int t = 0; t < TPB; ++t) {
                float wx = 1.0f - fabsf(px - tx[t]);              // may be < 0
                float hy = fmaxf(1.0f - fabsf(py - ty[t]), 0.0f); // clamped
                best[t] = fmaxf(best[t], wx * hy);  // wx<0 => product<=0, discarded
            }
        }
    } else {
        // ---- generic fallback: full IoU, streaming loop ----
        const int n1 = min(N, n0 + CHUNK);
        float x1[TPB], y1[TPB], x2[TPB], y2[TPB], a[TPB];
#pragma unroll
        for (int t = 0; t < TPB; ++t) {
            int j = jbase + t * BLOCK;
            int js = (j < M) ? j : (M - 1);
            float4 b = tf[js];
            x1[t] = b.x; y1[t] = b.y; x2[t] = b.z; y2[t] = b.w;
            a[t] = ta[js];
        }
        for (int k = n0; k < n1; ++k) {
            float4 p = pf[k];
            float par = pa[k];
#pragma unroll
            for (int t = 0; t < TPB; ++t) {
                float lx = fmaxf(p.x, x1[t]);
                float ly = fmaxf(p.y, y1[t]);
                float rx = fminf(p.z, x2[t]);
                float ry = fminf(p.w, y2[t]);
                float w  = fmaxf(rx - lx, 0.0f);
                float h  = fmaxf(ry - ly, 0.0f);
                float inter = w * h;
                float uni   = (par + a[t]) - inter;   // >= 1 (EPS forces dims >= 1)
                best[t] = fmaxf(best[t], inter * __builtin_amdgcn_rcpf(uni));
            }
        }
    }

    float* prow = partial + (size_t)blockIdx.y * M;
#pragma unroll
    for (int t = 0; t < TPB; ++t) {
        int j = jbase + t * BLOCK;
        if (j < M) prow[j] = best[t];
    }
}

__global__ __launch_bounds__(BLOCK) void reduce_kernel(
    const float* __restrict__ partial,  // [S][M]
    const int* __restrict__ flag,
    float* __restrict__ out, int M, int S)
{
    __shared__ float sd[RED_SG][RED_COLS];
    const int c  = threadIdx.x & (RED_COLS - 1);
    const int sg = threadIdx.x / RED_COLS;
    const int j  = blockIdx.x * RED_COLS + c;

    float b = 0.0f;
    if (j < M) {
#pragma unroll 8
        for (int s = sg; s < S; s += RED_SG)
            b = fmaxf(b, partial[(size_t)s * M + j]);
    }
    sd[sg][c] = b;
    __syncthreads();
    if (sg == 0 && j < M) {
        float m = sd[0][c];
#pragma unroll
        for (int g = 1; g < RED_SG; ++g) m = fmaxf(m, sd[g][c]);
        float loss;
        if (*flag == 0)
            loss = 1.0f - m * __builtin_amdgcn_rcpf(2.0f - m);  // IoU = i/(2-i), unit boxes
        else
            loss = 1.0f - m;
        out[j] = loss;
    }
}

extern "C" void kernel_launch(void* const* d_in, const int* in_sizes, int n_in,
                              void* d_out, int out_size, void* d_ws, size_t ws_size,
                              hipStream_t stream) {
    const float* pred = (const float*)d_in[0];
    const float* trub = (const float*)d_in[1];
    float* out = (float*)d_out;
    const int N = in_sizes[0] / 4;
    const int M = in_sizes[1] / 4;

    char* ws = (char*)d_ws;
    size_t off = 0;
    int*    flag = (int*)(ws + off);    off += 256;
    float2* pxy  = (float2*)(ws + off); off += (size_t)N * 8;
    float2* txy  = (float2*)(ws + off); off += (size_t)M * 8;
    float4* pf   = (float4*)(ws + off); off += (size_t)N * 16;
    float*  pa   = (float*) (ws + off); off += (size_t)N * 4;
    float4* tf   = (float4*)(ws + off); off += (size_t)M * 16;
    float*  ta   = (float*) (ws + off); off += (size_t)M * 4;
    off = (off + 255) & ~(size_t)255;
    float* partial = (float*)(ws + off);            // S * M floats

    hipMemsetAsync(flag, 0, sizeof(int), stream);   // capturable, replaces init kernel

    int mx = max(N, M);
    fix_kernel<<<(mx + BLOCK - 1) / BLOCK, BLOCK, 0, stream>>>(
        pred, trub, pxy, pf, pa, txy, tf, ta, flag, N, M);

    const int S = (N + CHUNK - 1) / CHUNK;          // splits = main grid.y
    dim3 grid((M + BLOCK * TPB - 1) / (BLOCK * TPB), S);
    iou_main<<<grid, BLOCK, 0, stream>>>(pxy, txy, pf, pa, tf, ta, flag, partial, N, M);

    reduce_kernel<<<(M + RED_COLS - 1) / RED_COLS, BLOCK, 0, stream>>>(
        partial, flag, out, M, S);
}

// Round 8
// 18.788 us; speedup vs baseline: 2.8357x; 1.7339x over previous
//
#include <hip/hip_runtime.h>

#define BLOCK 256
#define TPB 4            // true boxes (columns) per thread
#define CHUNK 64         // pred boxes per block (staged in LDS by wave 0)
#define WAVES (BLOCK / 64)

__global__ void init_out(float* __restrict__ out, int M) {
    int i = blockIdx.x * blockDim.x + threadIdx.x;
    if (i < M) out[i] = 1.0f;    // atomicMin identity; losses are in [0,1]
}

__global__ __launch_bounds__(BLOCK) void iou_fused(
    const float* __restrict__ pred,   // [N,4] raw
    const float* __restrict__ trub,   // [M,4] raw
    float* __restrict__ out,          // [M], pre-set to 1.0f by init_out
    int N, int M)
{
    __shared__ float2 sp[CHUNK];      // fixed pred corners (fast path)
    __shared__ float4 sbox[CHUNK];    // fixed pred box (generic path)
    __shared__ float  sarea[CHUNK];   // pred areas (generic path)
    __shared__ int    sbadw[WAVES];   // per-wave "not unit box" flags

    const int tid = threadIdx.x;
    const int n0  = blockIdx.y * CHUNK;

    // ---- cooperative load+fix of this block's CHUNK preds (lanes of wave 0) ----
    bool bad = false;
    if (tid < CHUNK) {
        int k = n0 + tid; if (k >= N) k = N - 1;   // clamp: duplicate, harmless for max
        float4 b = reinterpret_cast<const float4*>(pred)[k];
        float x1 = fminf(b.x, b.z), y1 = fminf(b.y, b.w);
        float x2 = fmaxf(b.x, b.z), y2 = fmaxf(b.y, b.w);
        bad = (x2 > x1 + 1.0f) || (y2 > y1 + 1.0f);   // unit-box property check
        x2 = fmaxf(x2, x1 + 1.0f); y2 = fmaxf(y2, y1 + 1.0f);  // EPS = 1.0
        sp[tid]    = make_float2(x1, y1);
        sbox[tid]  = make_float4(x1, y1, x2, y2);
        sarea[tid] = (x2 - x1) * (y2 - y1);
    }

    // ---- per-thread load+fix of TPB true boxes (registers) ----
    const int jbase = blockIdx.x * (BLOCK * TPB) + tid;
    float tx[TPB], ty[TPB], X2[TPB], Y2[TPB], TA[TPB];
#pragma unroll
    for (int t = 0; t < TPB; ++t) {
        int j = jbase + t * BLOCK; if (j >= M) j = M - 1;
        float4 b = reinterpret_cast<const float4*>(trub)[j];
        float x1 = fminf(b.x, b.z), y1 = fminf(b.y, b.w);
        float x2 = fmaxf(b.x, b.z), y2 = fmaxf(b.y, b.w);
        bad = bad || (x2 > x1 + 1.0f) || (y2 > y1 + 1.0f);
        x2 = fmaxf(x2, x1 + 1.0f); y2 = fmaxf(y2, y1 + 1.0f);
        tx[t] = x1; ty[t] = y1; X2[t] = x2; Y2[t] = y2;
        TA[t] = (x2 - x1) * (y2 - y1);
    }

    // ---- block-uniform fast/generic decision: per-wave vote, one barrier ----
    int anybad = __any(bad) ? 1 : 0;
    if ((tid & 63) == 0) sbadw[tid >> 6] = anybad;
    __syncthreads();
    int blkbad = 0;
#pragma unroll
    for (int w = 0; w < WAVES; ++w) blkbad |= sbadw[w];

    float best[TPB];
#pragma unroll
    for (int t = 0; t < TPB; ++t) best[t] = 0.0f;

    if (!blkbad) {
        // ---- fast path: all boxes exactly 1x1 -> track max INTERSECTION ----
#pragma unroll
        for (int k = 0; k < CHUNK; ++k) {
            float2 p = sp[k];                      // LDS broadcast (same addr, no conflict)
#pragma unroll
            for (int t = 0; t < TPB; ++t) {
                float wx = 1.0f - fabsf(p.x - tx[t]);               // may be < 0
                float hy = fmaxf(1.0f - fabsf(p.y - ty[t]), 0.0f);  // clamped
                best[t] = fmaxf(best[t], wx * hy);  // wx<0 => product<=0, discarded
            }
        }
        // intersection -> IoU once per column: IoU = i / (2 - i), 2-i in [1,2]
#pragma unroll
        for (int t = 0; t < TPB; ++t)
            best[t] = best[t] * __builtin_amdgcn_rcpf(2.0f - best[t]);
    } else {
        // ---- generic path: full IoU from staged fixed boxes ----
#pragma unroll 4
        for (int k = 0; k < CHUNK; ++k) {
            float4 p  = sbox[k];
            float  pa = sarea[k];
#pragma unroll
            for (int t = 0; t < TPB; ++t) {
                float lx = fmaxf(p.x, tx[t]);
                float ly = fmaxf(p.y, ty[t]);
                float rx = fminf(p.z, X2[t]);
                float ry = fminf(p.w, Y2[t]);
                float w  = fmaxf(rx - lx, 0.0f);
                float h  = fmaxf(ry - ly, 0.0f);
                float inter = w * h;
                float uni   = (pa + TA[t]) - inter;   // >= 1 (EPS forces dims >= 1)
                best[t] = fmaxf(best[t], inter * __builtin_amdgcn_rcpf(uni));
            }
        }
    }

    // ---- combine across pred-splits: atomic min of loss (int bits, all >= 0) ----
#pragma unroll
    for (int t = 0; t < TPB; ++t) {
        int j = jbase + t * BLOCK;
        if (j < M) {
            float loss = 1.0f - best[t];
            atomicMin(reinterpret_cast<int*>(out) + j, __float_as_int(loss));
        }
    }
}

extern "C" void kernel_launch(void* const* d_in, const int* in_sizes, int n_in,
                              void* d_out, int out_size, void* d_ws, size_t ws_size,
                              hipStream_t stream) {
    const float* pred = (const float*)d_in[0];
    const float* trub = (const float*)d_in[1];
    float* out = (float*)d_out;
    const int N = in_sizes[0] / 4;
    const int M = in_sizes[1] / 4;

    init_out<<<(M + BLOCK - 1) / BLOCK, BLOCK, 0, stream>>>(out, M);

    dim3 grid((M + BLOCK * TPB - 1) / (BLOCK * TPB),   // 8  column-groups
              (N + CHUNK - 1) / CHUNK);                // 128 pred-chunks
    iou_fused<<<grid, BLOCK, 0, stream>>>(pred, trub, out, N, M);
}